// Round 3
// baseline (601.638 us; speedup 1.0000x reference)
//
#include <hip/hip_runtime.h>
#include <math.h>

#define N_PTS   8192
#define KNN     30
#define CAPG    104     // max stored candidates (lambda=48, +8 sigma)
#define STR     105     // LDS row stride in u64
#define BLOCK   128     // 2 waves per block
#define NZ      64
#define NY      64
#define NBKT    (NZ * NY)
#define CLO     -4.0f
#define CSC     8.0f
#define INVCSC  0.125f
#define LAMBDA  48.0f
#define HBIN    16      // tot >= 2048 -> heavy single-query 64-lane unit
#define NQUEUE  8
#define NWAVES  8192    // 4096 blocks x 2 waves = full residency (32 waves/CU)
#define NQ      32768

// ws layout (bytes):
//   S      f4[4*8192]   @ 0        (524288)
//   O      i32[4*8192]  @ 524288   (131072)
//   bstart i32[4*4097]  @ 655360   (65552)
//   ghist  i32[4*4096]  @ 720912   (65536)  \
//   chist  i32[64]      @ 786448   (256)     | zeroed in one memset
//   ticket i32[8]       @ 786704   (32)      |
//   ctrl   i32[2]       @ 786736   (8)      /
//   gcur   i32[4*4096]  @ 786744   (65536)  (init by prep_scan)
//   ccur   i32[64]      @ 852280   (256)    (init by order_scan)
//   R2     f32[32768]   @ 852536   (131072)
//   bins   u8 [32768]   @ 983608   (32768)
//   Qorder i32[32772]   @ 1016376  (131088) -> total 1147464 B
#define WS_S    0
#define WS_O    524288
#define WS_BS   655360
#define WS_GH   720912
#define WS_CH   786448
#define WS_TK   786704
#define WS_CTL  786736
#define WS_ZEND 786744
#define WS_GC   786744
#define WS_CC   852280
#define WS_R2   852536
#define WS_BIN  983608
#define WS_QO   1016376

__device__ __forceinline__ int clampi(int v, int lo, int hi) {
    return v < lo ? lo : (v > hi ? hi : v);
}
__device__ __forceinline__ int bucket_of(float pz, float py) {
    int zb = clampi((int)floorf((pz - CLO) * CSC), 0, NZ - 1);
    int yb = clampi((int)floorf((py - CLO) * CSC), 0, NY - 1);
    return (zb << 6) | yb;
}

// fp64 3x3 symmetric smallest-eigenvector epilogue + sign fix + store.
__device__ __forceinline__ void normal_epilogue(double sx, double sy, double sz,
        double sxx, double sxy, double sxz, double syy, double syz, double szz,
        double qx, double qy, double qz, float* ob, int oi) {
    const double kinv = 1.0 / (double)KNN;
    double m00 = sxx - sx * sx * kinv;
    double m11 = syy - sy * sy * kinv;
    double m22 = szz - sz * sz * kinv;
    double m01 = sxy - sx * sy * kinv;
    double m02 = sxz - sx * sz * kinv;
    double m12 = syz - sy * sz * kinv;

    double nx = 1.0, ny = 0.0, nz = 0.0;
    double q3 = (m00 + m11 + m22) / 3.0;
    double p1 = m01 * m01 + m02 * m02 + m12 * m12;
    double d00 = m00 - q3, d11 = m11 - q3, d22 = m22 - q3;
    double p2 = d00 * d00 + d11 * d11 + d22 * d22 + 2.0 * p1;
    if (p2 > 1e-280) {
        double pp = sqrt(p2 / 6.0);
        double ip = 1.0 / pp;
        double b00 = d00 * ip, b11 = d11 * ip, b22 = d22 * ip;
        double b01 = m01 * ip, b02 = m02 * ip, b12 = m12 * ip;
        double detB = b00 * (b11 * b22 - b12 * b12)
                    - b01 * (b01 * b22 - b12 * b02)
                    + b02 * (b01 * b12 - b11 * b02);
        double rr = 0.5 * detB;
        rr = rr < -1.0 ? -1.0 : (rr > 1.0 ? 1.0 : rr);
        double phi = acos(rr) / 3.0;
        double lam = q3 + 2.0 * pp * cos(phi + 2.0943951023931953); // smallest eig
        double a00 = m00 - lam, a11 = m11 - lam, a22 = m22 - lam;
        double v0x = m01 * m12 - m02 * a11, v0y = m02 * m01 - a00 * m12, v0z = a00 * a11 - m01 * m01;
        double v1x = m01 * a22 - m02 * m12, v1y = m02 * m02 - a00 * a22, v1z = a00 * m12 - m01 * m02;
        double v2x = a11 * a22 - m12 * m12, v2y = m12 * m02 - m01 * a22, v2z = m01 * m12 - a11 * m02;
        double n0 = v0x * v0x + v0y * v0y + v0z * v0z;
        double n1 = v1x * v1x + v1y * v1y + v1z * v1z;
        double n2 = v2x * v2x + v2y * v2y + v2z * v2z;
        double bx = v0x, by = v0y, bz = v0z, bn = n0;
        if (n1 > bn) { bx = v1x; by = v1y; bz = v1z; bn = n1; }
        if (n2 > bn) { bx = v2x; by = v2y; bz = v2z; bn = n2; }
        if (bn > 1e-280) {
            double inv = 1.0 / sqrt(bn);
            nx = bx * inv; ny = by * inv; nz = bz * inv;
        }
    }
    double dq = -(qx * nx + qy * ny + qz * nz);
    if (dq < 0.0) { nx = -nx; ny = -ny; nz = -nz; }

    ob[3 * N_PTS + oi] = (float)nx;
    ob[4 * N_PTS + oi] = (float)ny;
    ob[5 * N_PTS + oi] = (float)nz;
}

// ---------------------------------------------------------------------------
// Prep A: full-chip. Copy x -> out ch0..2, histogram (z,y) buckets.
// ---------------------------------------------------------------------------
__global__ __launch_bounds__(256) void prep_hist_kernel(const float* __restrict__ x,
                                                        float* __restrict__ out,
                                                        int* __restrict__ ghist) {
    const int i = blockIdx.x * 256 + threadIdx.x;     // 0..32767
    const int b = i >> 13;
    const int p = i & (N_PTS - 1);
    const float* xb = x + (size_t)b * 3 * N_PTS;
    float* ob = out + (size_t)b * 6 * N_PTS;
    float px = xb[p], py = xb[N_PTS + p], pz = xb[2 * N_PTS + p];
    ob[p]             = px;
    ob[N_PTS + p]     = py;
    ob[2 * N_PTS + p] = pz;
    atomicAdd(&ghist[(b << 12) + bucket_of(pz, py)], 1);
}

// ---------------------------------------------------------------------------
// Prep B: per-batch exclusive scan of 4096-bucket histogram.
// ---------------------------------------------------------------------------
__global__ __launch_bounds__(1024) void prep_scan_kernel(const int* __restrict__ ghist,
                                                         int* __restrict__ bstart,
                                                         int* __restrict__ gcur) {
    __shared__ int wsum[16];
    const int b = blockIdx.x;
    const int t = threadIdx.x;
    const int wid = t >> 6, lane = t & 63;
    const int* gh = ghist + (b << 12);

    int l0 = gh[4 * t], l1 = gh[4 * t + 1], l2 = gh[4 * t + 2], l3 = gh[4 * t + 3];
    int s = l0 + l1 + l2 + l3;
    int sum = s;
    #pragma unroll
    for (int off = 1; off < 64; off <<= 1) {
        int v = __shfl_up(sum, off);
        if (lane >= off) sum += v;
    }
    if (lane == 63) wsum[wid] = sum;
    __syncthreads();
    if (t == 0) {
        int run = 0;
        #pragma unroll
        for (int k = 0; k < 16; ++k) { int v = wsum[k]; wsum[k] = run; run += v; }
    }
    __syncthreads();
    int base = wsum[wid] + (sum - s);
    int b0 = base, b1 = base + l0, b2 = b1 + l1, b3 = b2 + l2;
    int* bsb = bstart + b * (NBKT + 1);
    int* gc  = gcur + (b << 12);
    bsb[4 * t] = b0; bsb[4 * t + 1] = b1; bsb[4 * t + 2] = b2; bsb[4 * t + 3] = b3;
    gc[4 * t]  = b0; gc[4 * t + 1]  = b1; gc[4 * t + 2]  = b2; gc[4 * t + 3]  = b3;
    if (t == 1023) bsb[NBKT] = N_PTS;
}

// ---------------------------------------------------------------------------
// Prep C: scatter + per-query radius solve + cost bin (fused; full-chip).
// Query identity == sorted position dst. Scalar Simpson-9 bisection.
// ---------------------------------------------------------------------------
__global__ __launch_bounds__(256) void prep_scatter_cost(const float* __restrict__ x,
                                                         float4* __restrict__ S,
                                                         int* __restrict__ O,
                                                         int* __restrict__ gcur,
                                                         const int* __restrict__ bstart,
                                                         float* __restrict__ R2,
                                                         unsigned char* __restrict__ bins,
                                                         int* __restrict__ chist) {
    const int i = blockIdx.x * 256 + threadIdx.x;     // 0..32767
    const int b = i >> 13;
    const int p = i & (N_PTS - 1);
    const float* xb = x + (size_t)b * 3 * N_PTS;
    float px = xb[p], py = xb[N_PTS + p], pz = xb[2 * N_PTS + p];
    int bk = bucket_of(pz, py);
    int dst = atomicAdd(&gcur[(b << 12) + bk], 1);
    float xx = __fadd_rn(__fadd_rn(__fmul_rn(px, px), __fmul_rn(py, py)),
                         __fmul_rn(pz, pz));
    S[((size_t)b << 13) + dst] = make_float4(px, py, pz, xx);
    O[((size_t)b << 13) + dst] = p;

    // scalar radius solve: lambda(r)=48 (Gaussian ball mass)
    const float c = fmaxf(sqrtf(xx), 1e-3f);
    float rlo = 0.05f, rhi = 6.0f;
    for (int it = 0; it < 14; ++it) {
        float r = 0.5f * (rlo + rhi);
        float slo = fmaxf(c - r, 0.0f);
        float h = (c + r - slo) * 0.125f;
        float f = 0.0f;
        #pragma unroll
        for (int l = 0; l <= 8; ++l) {
            float sq = slo + h * (float)l;
            float cs = c - sq;
            float hh = fmaxf(fminf((r * r - cs * cs) * (0.5f / c), 2.0f * sq), 0.0f);
            float wq = (l == 0 || l == 8) ? 1.0f : ((l & 1) ? 4.0f : 2.0f);
            f += wq * __expf(-0.5f * sq * sq) * sq * hh;
        }
        float lam = 1089.3f * f * h;       // 520.1 * 2*pi / 3
        if (lam < LAMBDA) rlo = r; else rhi = r;
    }
    float rad = rhi * 1.02f;
    float r2 = rad * rad;
    R2[(b << 13) + dst] = r2;

    // rectangle window candidate count -> cost bin
    float w = __fmaf_rn(sqrtf(r2), 1.002f, 1e-3f);
    const int* bs = bstart + b * (NBKT + 1);
    int zlo = clampi((int)floorf((pz - w - CLO) * CSC), 0, NZ - 1);
    int zhi = clampi((int)floorf((pz + w - CLO) * CSC), 0, NZ - 1);
    int ylo = clampi((int)floorf((py - w - CLO) * CSC), 0, NY - 1);
    int yhi = clampi((int)floorf((py + w - CLO) * CSC), 0, NY - 1);
    int tot = 0;
    for (int zb = zlo; zb <= zhi; ++zb)
        tot += bs[(zb << 6) + yhi + 1] - bs[(zb << 6) + ylo];
    int bin = tot >> 7; if (bin > 63) bin = 63;
    bins[(b << 13) + dst] = (unsigned char)bin;
    atomicAdd(&chist[bin], 1);
}

// ---------------------------------------------------------------------------
// Prep D: descending-cost scan of 64 bins (1 wave). Writes ccur starts,
// ctrl[0]=H (heavy count), ctrl[1]=U (total work units), Qorder pad.
// ---------------------------------------------------------------------------
__global__ __launch_bounds__(64) void order_scan_kernel(const int* __restrict__ chist,
                                                        int* __restrict__ ccur,
                                                        int* __restrict__ ctrl,
                                                        int* __restrict__ Qorder) {
    const int lane = threadIdx.x;
    const int bin  = 63 - lane;          // descending-cost order
    int v = chist[bin];
    int incl = v;
    #pragma unroll
    for (int off = 1; off < 64; off <<= 1) {
        int tv = __shfl_up(incl, off);
        if (lane >= off) incl += tv;
    }
    ccur[bin] = incl - v;                // exclusive prefix in desc order
    if (bin == HBIN) {
        int H = incl;                    // queries with tot >= 2048
        ctrl[0] = H;
        int rem = NQ - H;
        ctrl[1] = H + ((rem + 3) >> 2);  // U = heavy singles + quads
    }
    if (lane < 3) Qorder[NQ + lane] = -1;   // quad-tail padding
}

// ---------------------------------------------------------------------------
// Prep E: scatter qids into Qorder by descending cost bin (full-chip).
// ---------------------------------------------------------------------------
__global__ __launch_bounds__(256) void order_scatter_kernel(const unsigned char* __restrict__ bins,
                                                            int* __restrict__ ccur,
                                                            int* __restrict__ Qorder) {
    const int i = blockIdx.x * 256 + threadIdx.x;     // qid 0..32767
    int bin = bins[i];
    int slot = atomicAdd(&ccur[bin], 1);
    Qorder[slot] = i;
}

// ---------------------------------------------------------------------------
// Main: per-wave work units, cost-ordered. Unit u < H: one heavy query,
// 64 lanes. Unit u >= H: quad of 4 similar-cost queries, 16 lanes each.
// Static seed (wave wid takes unit wid) + dynamic striped-ticket refill.
// No block barriers (wave-local LDS ordering + lgkmcnt waits only).
// ---------------------------------------------------------------------------
__global__ __launch_bounds__(BLOCK, 8) void knn_main(const float4* __restrict__ S,
                                                     const int* __restrict__ O,
                                                     const int* __restrict__ bstart,
                                                     const float* __restrict__ R2,
                                                     const int* __restrict__ Qorder,
                                                     const int* __restrict__ ctrl,
                                                     int* __restrict__ tickets,
                                                     float* __restrict__ out) {
    __shared__ unsigned long long ldk[8 * STR];

    const int t    = threadIdx.x;
    const int wv   = t >> 6;
    const int lane = t & 63;
    const int l16  = t & 15;
    const int gw   = lane >> 4;
    const int gsh  = lane & ~15;
    const int H    = ctrl[0];
    const int U    = ctrl[1];
    const int q    = blockIdx.x & (NQUEUE - 1);
    unsigned long long* __restrict__ ldw = ldk + (wv << 2) * STR;  // wave's 4 rows
    unsigned long long* __restrict__ ldg = ldw + gw * STR;         // group's row

    int u = (blockIdx.x << 1) | wv;      // static seed: wave wid -> unit wid
    bool first = true;

    for (;;) {
        if (!first) {
            int tk = 0;
            if (lane == 0) tk = atomicAdd(&tickets[q], 1);
            tk = __builtin_amdgcn_readfirstlane(tk);
            u = NWAVES + q + tk * NQUEUE;
        }
        first = false;
        if (u >= U) break;

        if (u < H) {
            // ================= heavy: one query, 64 lanes =================
            const int qid = Qorder[u];
            const int b   = qid >> 13;
            const int pos = qid & (N_PTS - 1);
            const float4* __restrict__ P  = S + ((size_t)b << 13);
            const int*    __restrict__ Ob = O + ((size_t)b << 13);
            const int*    __restrict__ bs = bstart + b * (NBKT + 1);
            const float4 qp = P[pos];
            const int    oi = Ob[pos];
            float r2 = R2[qid];
            int cnt = 0;

            for (;;) {
                cnt = 0;
                float w  = __fmaf_rn(sqrtf(r2), 1.002f, 1e-3f);
                float w2 = w * w;
                int zlo = clampi((int)floorf((qp.z - w - CLO) * CSC), 0, NZ - 1);
                int zhi = clampi((int)floorf((qp.z + w - CLO) * CSC), 0, NZ - 1);
                for (int zb = zlo; zb <= zhi; ++zb) {
                    float z0  = CLO + (float)zb * INVCSC;
                    float dzr = fmaxf(fmaxf(z0 - qp.z, qp.z - (z0 + INVCSC)), 0.0f) * 0.999f;
                    float hw2 = w2 - dzr * dzr;
                    if (hw2 <= 0.0f) continue;
                    float hw  = __fmaf_rn(sqrtf(hw2), 1.001f, 1e-4f);
                    int ylo = clampi((int)floorf((qp.y - hw - CLO) * CSC), 0, NY - 1);
                    int yhi = clampi((int)floorf((qp.y + hw - CLO) * CSC), 0, NY - 1);
                    int lo = bs[(zb << 6) + ylo];
                    int hi = bs[(zb << 6) + yhi + 1];
                    int smax = (hi - lo + 127) >> 7;   // 128 cand/iter
                    for (int s = 0; s < smax; ++s) {
                        int j1  = lo + (s << 7) + lane;
                        int j2  = j1 + 64;
                        int jc1 = j1 < hi ? j1 : hi - 1;
                        int jc2 = j2 < hi ? j2 : hi - 1;
                        float4 p1 = P[jc1];
                        float4 p2 = P[jc2];
                        float mm1 = __fmaf_rn(qp.z, p1.z, __fmaf_rn(qp.y, p1.y, __fmul_rn(qp.x, p1.x)));
                        float d1  = __fsub_rn(__fadd_rn(qp.w, p1.w), __fmul_rn(2.0f, mm1));
                        float mm2 = __fmaf_rn(qp.z, p2.z, __fmaf_rn(qp.y, p2.y, __fmul_rn(qp.x, p2.x)));
                        float d2  = __fsub_rn(__fadd_rn(qp.w, p2.w), __fmul_rn(2.0f, mm2));
                        bool hit1 = (j1 < hi) && (d1 <= r2);
                        bool hit2 = (j2 < hi) && (d2 <= r2);
                        unsigned long long m1 = __ballot(hit1);
                        if (hit1) {
                            int slot = cnt + __popcll(m1 & ((1ull << lane) - 1ull));
                            if (slot < CAPG) {
                                unsigned uu = __float_as_uint(d1);
                                uu = (uu & 0x80000000u) ? ~uu : (uu | 0x80000000u);
                                ldw[slot] = ((unsigned long long)uu << 28) | (unsigned long long)jc1;
                            }
                        }
                        cnt += __popcll(m1);
                        unsigned long long m2 = __ballot(hit2);
                        if (hit2) {
                            int slot = cnt + __popcll(m2 & ((1ull << lane) - 1ull));
                            if (slot < CAPG) {
                                unsigned uu = __float_as_uint(d2);
                                uu = (uu & 0x80000000u) ? ~uu : (uu | 0x80000000u);
                                ldw[slot] = ((unsigned long long)uu << 28) | (unsigned long long)jc2;
                            }
                        }
                        cnt += __popcll(m2);
                    }
                }
                if (cnt >= KNN && cnt <= CAPG) break;
                r2 = (cnt < KNN) ? r2 * 1.6f : r2 * 0.82f;
            }

            for (int k = lane; k < cnt; k += 64) {
                unsigned long long key = ldw[k];
                int jc = (int)(key & 0x3FFFull);
                ldw[k] = (key & ~0x0FFFFFFFull) | ((unsigned long long)Ob[jc] << 14) | (unsigned long long)jc;
            }
            __builtin_amdgcn_wave_barrier();
            asm volatile("s_waitcnt lgkmcnt(0)" ::: "memory");

            const double qx = (double)qp.x, qy = (double)qp.y, qz = (double)qp.z;
            double sx = 0.0, sy = 0.0, sz = 0.0;
            double sxx = 0.0, sxy = 0.0, sxz = 0.0, syy = 0.0, syz = 0.0, szz = 0.0;
            for (int k = lane; k < cnt; k += 64) {
                unsigned long long key = ldw[k];
                int rank = 0;
                for (int uu = 0; uu < cnt; ++uu) rank += (ldw[uu] < key) ? 1 : 0;
                if (rank < KNN) {
                    float4 p = P[(int)(key & 0x3FFFull)];
                    double ax = (double)p.x - qx, ay = (double)p.y - qy, az = (double)p.z - qz;
                    sx += ax; sy += ay; sz += az;
                    sxx = fma(ax, ax, sxx); sxy = fma(ax, ay, sxy); sxz = fma(ax, az, sxz);
                    syy = fma(ay, ay, syy); syz = fma(ay, az, syz); szz = fma(az, az, szz);
                }
            }
            #pragma unroll
            for (int off = 1; off < 64; off <<= 1) {
                sx  += __shfl_xor(sx,  off, 64); sy  += __shfl_xor(sy,  off, 64); sz  += __shfl_xor(sz,  off, 64);
                sxx += __shfl_xor(sxx, off, 64); sxy += __shfl_xor(sxy, off, 64); sxz += __shfl_xor(sxz, off, 64);
                syy += __shfl_xor(syy, off, 64); syz += __shfl_xor(syz, off, 64); szz += __shfl_xor(szz, off, 64);
            }
            if (lane == 0) {
                float* ob = out + (size_t)b * 6 * N_PTS;
                normal_epilogue(sx, sy, sz, sxx, sxy, sxz, syy, syz, szz, qx, qy, qz, ob, oi);
            }
        } else {
            // ============== quad: 4 similar-cost queries, 16 lanes each ==============
            const int base = H + ((u - H) << 2);
            const int qraw = Qorder[base + gw];
            const bool ok  = qraw >= 0;
            const int qid  = ok ? qraw : 0;
            const int b    = qid >> 13;
            const int pos  = qid & (N_PTS - 1);
            const float4* __restrict__ P  = S + ((size_t)b << 13);
            const int*    __restrict__ Ob = O + ((size_t)b << 13);
            const int*    __restrict__ bs = bstart + b * (NBKT + 1);
            const float4 qp = P[pos];
            const int    oi = Ob[pos];
            float r2 = R2[qid];

            int  cnt = 0;
            bool active = ok;
            for (;;) {
                if (active) {
                    cnt = 0;
                    float w  = __fmaf_rn(sqrtf(r2), 1.002f, 1e-3f);
                    float w2 = w * w;
                    int zlo = clampi((int)floorf((qp.z - w - CLO) * CSC), 0, NZ - 1);
                    int zhi = clampi((int)floorf((qp.z + w - CLO) * CSC), 0, NZ - 1);
                    for (int zb = zlo; zb <= zhi; ++zb) {
                        float z0  = CLO + (float)zb * INVCSC;
                        float dzr = fmaxf(fmaxf(z0 - qp.z, qp.z - (z0 + INVCSC)), 0.0f) * 0.999f;
                        float hw2 = w2 - dzr * dzr;
                        if (hw2 <= 0.0f) continue;
                        float hw  = __fmaf_rn(sqrtf(hw2), 1.001f, 1e-4f);
                        int ylo = clampi((int)floorf((qp.y - hw - CLO) * CSC), 0, NY - 1);
                        int yhi = clampi((int)floorf((qp.y + hw - CLO) * CSC), 0, NY - 1);
                        int lo = bs[(zb << 6) + ylo];
                        int hi = bs[(zb << 6) + yhi + 1];
                        int smax = (hi - lo + 31) >> 5;   // 32 cand/iter
                        for (int s = 0; s < smax; ++s) {
                            int j1  = lo + (s << 5) + l16;
                            int j2  = j1 + 16;
                            int jc1 = j1 < hi ? j1 : hi - 1;
                            int jc2 = j2 < hi ? j2 : hi - 1;
                            float4 p1 = P[jc1];
                            float4 p2 = P[jc2];
                            float mm1 = __fmaf_rn(qp.z, p1.z, __fmaf_rn(qp.y, p1.y, __fmul_rn(qp.x, p1.x)));
                            float d1  = __fsub_rn(__fadd_rn(qp.w, p1.w), __fmul_rn(2.0f, mm1));
                            float mm2 = __fmaf_rn(qp.z, p2.z, __fmaf_rn(qp.y, p2.y, __fmul_rn(qp.x, p2.x)));
                            float d2  = __fsub_rn(__fadd_rn(qp.w, p2.w), __fmul_rn(2.0f, mm2));
                            bool hit1 = (j1 < hi) && (d1 <= r2);
                            bool hit2 = (j2 < hi) && (d2 <= r2);
                            unsigned long long m1 = __ballot(hit1);
                            unsigned sub1 = (unsigned)((m1 >> gsh) & 0xFFFFull);
                            if (hit1) {
                                int slot = cnt + __popc(sub1 & ((1u << l16) - 1u));
                                if (slot < CAPG) {
                                    unsigned uu = __float_as_uint(d1);
                                    uu = (uu & 0x80000000u) ? ~uu : (uu | 0x80000000u);
                                    ldg[slot] = ((unsigned long long)uu << 28) | (unsigned long long)jc1;
                                }
                            }
                            cnt += __popc(sub1);
                            unsigned long long m2 = __ballot(hit2);
                            unsigned sub2 = (unsigned)((m2 >> gsh) & 0xFFFFull);
                            if (hit2) {
                                int slot = cnt + __popc(sub2 & ((1u << l16) - 1u));
                                if (slot < CAPG) {
                                    unsigned uu = __float_as_uint(d2);
                                    uu = (uu & 0x80000000u) ? ~uu : (uu | 0x80000000u);
                                    ldg[slot] = ((unsigned long long)uu << 28) | (unsigned long long)jc2;
                                }
                            }
                            cnt += __popc(sub2);
                        }
                    }
                }
                bool bad = active && (cnt < KNN || cnt > CAPG);
                if (__ballot(bad) == 0ULL) break;
                active = bad;
                if (active) r2 = (cnt < KNN) ? r2 * 1.6f : r2 * 0.82f;
            }

            for (int k = l16; k < cnt; k += 16) {
                unsigned long long key = ldg[k];
                int jc = (int)(key & 0x3FFFull);
                ldg[k] = (key & ~0x0FFFFFFFull) | ((unsigned long long)Ob[jc] << 14) | (unsigned long long)jc;
            }
            __builtin_amdgcn_wave_barrier();
            asm volatile("s_waitcnt lgkmcnt(0)" ::: "memory");

            const double qx = (double)qp.x, qy = (double)qp.y, qz = (double)qp.z;
            double sx = 0.0, sy = 0.0, sz = 0.0;
            double sxx = 0.0, sxy = 0.0, sxz = 0.0, syy = 0.0, syz = 0.0, szz = 0.0;
            for (int k = l16; k < cnt; k += 16) {
                unsigned long long key = ldg[k];
                int rank = 0;
                for (int uu = 0; uu < cnt; ++uu) rank += (ldg[uu] < key) ? 1 : 0;
                if (rank < KNN) {
                    float4 p = P[(int)(key & 0x3FFFull)];
                    double ax = (double)p.x - qx, ay = (double)p.y - qy, az = (double)p.z - qz;
                    sx += ax; sy += ay; sz += az;
                    sxx = fma(ax, ax, sxx); sxy = fma(ax, ay, sxy); sxz = fma(ax, az, sxz);
                    syy = fma(ay, ay, syy); syz = fma(ay, az, syz); szz = fma(az, az, szz);
                }
            }
            #pragma unroll
            for (int off = 1; off < 16; off <<= 1) {
                sx  += __shfl_xor(sx,  off, 16); sy  += __shfl_xor(sy,  off, 16); sz  += __shfl_xor(sz,  off, 16);
                sxx += __shfl_xor(sxx, off, 16); sxy += __shfl_xor(sxy, off, 16); sxz += __shfl_xor(sxz, off, 16);
                syy += __shfl_xor(syy, off, 16); syz += __shfl_xor(syz, off, 16); szz += __shfl_xor(szz, off, 16);
            }
            if (l16 == 0 && ok) {
                float* ob = out + (size_t)b * 6 * N_PTS;
                normal_epilogue(sx, sy, sz, sxx, sxy, sxz, syy, syz, szz, qx, qy, qz, ob, oi);
            }
        }
    }
}

// ---------------------------------------------------------------------------
extern "C" void kernel_launch(void* const* d_in, const int* in_sizes, int n_in,
                              void* d_out, int out_size, void* d_ws, size_t ws_size,
                              hipStream_t stream) {
    const float* x = (const float*)d_in[0];
    float* out = (float*)d_out;
    char* ws = (char*)d_ws;
    float4*        S    = (float4*)(ws + WS_S);
    int*           O    = (int*)(ws + WS_O);
    int*           bsta = (int*)(ws + WS_BS);
    int*           gh   = (int*)(ws + WS_GH);
    int*           ch   = (int*)(ws + WS_CH);
    int*           tk   = (int*)(ws + WS_TK);
    int*           ctl  = (int*)(ws + WS_CTL);
    int*           gc   = (int*)(ws + WS_GC);
    int*           cc   = (int*)(ws + WS_CC);
    float*         r2a  = (float*)(ws + WS_R2);
    unsigned char* bins = (unsigned char*)(ws + WS_BIN);
    int*           qo   = (int*)(ws + WS_QO);

    hipMemsetAsync(ws + WS_GH, 0, WS_ZEND - WS_GH, stream);
    prep_hist_kernel    <<<dim3(128), dim3(256),  0, stream>>>(x, out, gh);
    prep_scan_kernel    <<<dim3(4),   dim3(1024), 0, stream>>>(gh, bsta, gc);
    prep_scatter_cost   <<<dim3(128), dim3(256),  0, stream>>>(x, S, O, gc, bsta, r2a, bins, ch);
    order_scan_kernel   <<<dim3(1),   dim3(64),   0, stream>>>(ch, cc, ctl, qo);
    order_scatter_kernel<<<dim3(128), dim3(256),  0, stream>>>(bins, cc, qo);
    knn_main            <<<dim3(4096), dim3(BLOCK), 0, stream>>>(S, O, bsta, r2a, qo, ctl, tk, out);
}

// Round 4
// 165.252 us; speedup vs baseline: 3.6407x; 3.6407x over previous
//
#include <hip/hip_runtime.h>
#include <math.h>

#define N_PTS   8192
#define KNN     30
#define CAPG    104     // max stored candidates per group (lambda=48, +8 sigma)
#define STR     105     // LDS row stride in u64
#define GROUPS  8       // queries per block
#define BLOCK   128     // 2 waves per block
#define NZ      64
#define NY      64
#define NBKT    (NZ * NY)
#define CLO     -4.0f
#define CSC     8.0f    // buckets per unit: bucket = floor((c - CLO) * CSC)
#define INVCSC  0.125f
#define LAMBDA  48.0f

// ws: S f4[32768]@0 | O i32[32768]@524288 | bstart i32[4*4097]@655360

__device__ __forceinline__ int clampi(int v, int lo, int hi) {
    return v < lo ? lo : (v > hi ? hi : v);
}
__device__ __forceinline__ int bucket_of(float pz, float py) {
    int zb = clampi((int)floorf((pz - CLO) * CSC), 0, NZ - 1);
    int yb = clampi((int)floorf((py - CLO) * CSC), 0, NY - 1);
    return (zb << 6) | yb;
}

// ---------------------------------------------------------------------------
// Fused prep: one block per batch (1024 threads). LDS hist -> in-block scan ->
// LDS-atomic counting-sort scatter. Also copies x into out ch0..2.
// ---------------------------------------------------------------------------
__global__ __launch_bounds__(1024) void prep_kernel(const float* __restrict__ x,
                                                    float4* __restrict__ S,
                                                    int* __restrict__ O,
                                                    int* __restrict__ bstart,
                                                    float* __restrict__ out) {
    __shared__ int hist[NBKT];    // 16 KB
    __shared__ int cur[NBKT];     // 16 KB (bucket cursors)
    __shared__ int wsum[16];

    const int b = blockIdx.x;
    const int t = threadIdx.x;
    const int wid = t >> 6, lane = t & 63;
    const float* xb = x + (size_t)b * 3 * N_PTS;
    float* ob = out + (size_t)b * 6 * N_PTS;

    for (int k = t; k < NBKT; k += 1024) hist[k] = 0;
    __syncthreads();

    float px[8], py[8], pz[8];
    int   bk[8];
    #pragma unroll
    for (int u = 0; u < 8; ++u) {
        int i = (u << 10) + t;
        px[u] = xb[i]; py[u] = xb[N_PTS + i]; pz[u] = xb[2 * N_PTS + i];
        bk[u] = bucket_of(pz[u], py[u]);
        atomicAdd(&hist[bk[u]], 1);
        ob[i]             = px[u];
        ob[N_PTS + i]     = py[u];
        ob[2 * N_PTS + i] = pz[u];
    }
    __syncthreads();

    // block scan: thread t owns buckets 4t..4t+3
    int l0 = hist[4 * t], l1 = hist[4 * t + 1], l2 = hist[4 * t + 2], l3 = hist[4 * t + 3];
    int s = l0 + l1 + l2 + l3;
    int sum = s;
    #pragma unroll
    for (int off = 1; off < 64; off <<= 1) {
        int v = __shfl_up(sum, off);
        if (lane >= off) sum += v;
    }
    if (lane == 63) wsum[wid] = sum;
    __syncthreads();
    if (t == 0) {
        int run = 0;
        #pragma unroll
        for (int k = 0; k < 16; ++k) { int v = wsum[k]; wsum[k] = run; run += v; }
    }
    __syncthreads();
    int base = wsum[wid] + (sum - s);     // exclusive prefix for this thread
    int b0 = base, b1 = base + l0, b2 = b1 + l1, b3 = b2 + l2;
    cur[4 * t] = b0; cur[4 * t + 1] = b1; cur[4 * t + 2] = b2; cur[4 * t + 3] = b3;
    int* bsb = bstart + b * (NBKT + 1);
    bsb[4 * t] = b0; bsb[4 * t + 1] = b1; bsb[4 * t + 2] = b2; bsb[4 * t + 3] = b3;
    if (t == 1023) bsb[NBKT] = N_PTS;
    __syncthreads();

    // scatter (xx_np = bitwise-numpy |p|^2, no fma)
    float4* Sb = S + ((size_t)b << 13);
    int*    Ob = O + ((size_t)b << 13);
    #pragma unroll
    for (int u = 0; u < 8; ++u) {
        int dst = atomicAdd(&cur[bk[u]], 1);
        float xx = __fadd_rn(__fadd_rn(__fmul_rn(px[u], px[u]), __fmul_rn(py[u], py[u])),
                             __fmul_rn(pz[u], pz[u]));
        Sb[dst] = make_float4(px[u], py[u], pz[u], xx);
        Ob[dst] = (u << 10) + t;
    }
}

// ---------------------------------------------------------------------------
// Main: 16 lanes/query, 8 queries/block. Lane-parallel radius solve; 2x-unrolled
// (z,y)-window segment scan with PER-ROW CIRCULAR Y-WINDOW (only provably
// non-hit rows/segments are skipped -> hit set, cnt, retries, and output are
// bit-identical to the rectangle scan); ballot-compact u64 keys; rank select;
// fp64 epilogue.
// ---------------------------------------------------------------------------
__global__ __launch_bounds__(BLOCK, 6) void knn_normal_kernel(const float4* __restrict__ S,
                                                              const int* __restrict__ O,
                                                              const int* __restrict__ bstart,
                                                              float* __restrict__ out) {
    __shared__ unsigned long long ldk[GROUPS * STR];

    const int t    = threadIdx.x;
    const int l16  = t & 15;
    const int g    = t >> 4;
    const int gsh  = (t & 63) & ~15;
    const int qblk = (blockIdx.x * 1031) & 4095;   // bijective swizzle: flatten tail
    const int qid  = qblk * GROUPS + g;
    const int b    = qid >> 13;
    const int pos  = qid & (N_PTS - 1);
    const float4* __restrict__ P  = S + ((size_t)b << 13);
    const int*    __restrict__ Ob = O + ((size_t)b << 13);
    const int*    __restrict__ bs = bstart + b * (NBKT + 1);
    const float4 qp = P[pos];
    const int    oi = Ob[pos];

    unsigned long long* __restrict__ ldg = ldk + g * STR;

    // ---- radius: solve lambda(r)=48 (Gaussian ball mass), lane-parallel Simpson-9
    const float c = fmaxf(sqrtf(qp.w), 1e-3f);
    float rlo = 0.05f, rhi = 6.0f;
    for (int it = 0; it < 14; ++it) {
        float r = 0.5f * (rlo + rhi);
        float slo = fmaxf(c - r, 0.0f);
        float h = (c + r - slo) * 0.125f;
        float f = 0.0f;
        if (l16 <= 8) {
            float sq = slo + h * (float)l16;
            float cs = c - sq;
            float hh = fmaxf(fminf((r * r - cs * cs) * (0.5f / c), 2.0f * sq), 0.0f);
            float w = (l16 == 0 || l16 == 8) ? 1.0f : ((l16 & 1) ? 4.0f : 2.0f);
            f = w * __expf(-0.5f * sq * sq) * sq * hh;
        }
        f += __shfl_xor(f, 1, 16); f += __shfl_xor(f, 2, 16);
        f += __shfl_xor(f, 4, 16); f += __shfl_xor(f, 8, 16);
        float lam = 1089.3f * f * h;       // 520.1 * 2*pi / 3
        if (lam < LAMBDA) rlo = r; else rhi = r;
    }
    float rad = rhi * 1.02f;
    float r2  = rad * rad;

    int  cnt = 0;
    bool active = true;

    for (;;) {
        if (active) {
            cnt = 0;
            float w  = __fmaf_rn(sqrtf(r2), 1.002f, 1e-3f);   // guard band; w > sqrt(r2)
            float w2 = __fmul_rn(w, w);
            int zlo = clampi((int)floorf((qp.z - w - CLO) * CSC), 0, NZ - 1);
            int zhi = clampi((int)floorf((qp.z + w - CLO) * CSC), 0, NZ - 1);
            for (int zb = zlo; zb <= zhi; ++zb) {
                // lower bound on |pz - qz| for any point in this z-row (0.999 guard)
                float z0  = CLO + (float)zb * INVCSC;
                float dzr = fmaxf(fmaxf(z0 - qp.z, qp.z - (z0 + INVCSC)), 0.0f) * 0.999f;
                float hw2 = __fmaf_rn(-dzr, dzr, w2);
                if (hw2 <= 0.0f) continue;            // row provably hit-free
                float hw  = __fmaf_rn(sqrtf(hw2), 1.001f, 1e-4f);   // inflated upper bound
                int ylo = clampi((int)floorf((qp.y - hw - CLO) * CSC), 0, NY - 1);
                int yhi = clampi((int)floorf((qp.y + hw - CLO) * CSC), 0, NY - 1);
                int lo = bs[(zb << 6) + ylo];
                int hi = bs[(zb << 6) + yhi + 1];
                int smax = (hi - lo + 31) >> 5;   // group-uniform, 32 cand/iter
                for (int s = 0; s < smax; ++s) {
                    int j1  = lo + (s << 5) + l16;
                    int j2  = j1 + 16;
                    int jc1 = j1 < hi ? j1 : hi - 1;
                    int jc2 = j2 < hi ? j2 : hi - 1;
                    float4 p1 = P[jc1];
                    float4 p2 = P[jc2];
                    float mm1 = __fmaf_rn(qp.z, p1.z, __fmaf_rn(qp.y, p1.y, __fmul_rn(qp.x, p1.x)));
                    float d1  = __fsub_rn(__fadd_rn(qp.w, p1.w), __fmul_rn(2.0f, mm1));
                    float mm2 = __fmaf_rn(qp.z, p2.z, __fmaf_rn(qp.y, p2.y, __fmul_rn(qp.x, p2.x)));
                    float d2  = __fsub_rn(__fadd_rn(qp.w, p2.w), __fmul_rn(2.0f, mm2));
                    bool hit1 = (j1 < hi) && (d1 <= r2);
                    bool hit2 = (j2 < hi) && (d2 <= r2);
                    unsigned long long m1 = __ballot(hit1);
                    unsigned sub1 = (unsigned)((m1 >> gsh) & 0xFFFFull);
                    if (hit1) {
                        int slot = cnt + __popc(sub1 & ((1u << l16) - 1u));
                        if (slot < CAPG) {
                            unsigned u = __float_as_uint(d1);
                            u = (u & 0x80000000u) ? ~u : (u | 0x80000000u);
                            ldg[slot] = ((unsigned long long)u << 28) | (unsigned long long)jc1;
                        }
                    }
                    cnt += __popc(sub1);
                    unsigned long long m2 = __ballot(hit2);
                    unsigned sub2 = (unsigned)((m2 >> gsh) & 0xFFFFull);
                    if (hit2) {
                        int slot = cnt + __popc(sub2 & ((1u << l16) - 1u));
                        if (slot < CAPG) {
                            unsigned u = __float_as_uint(d2);
                            u = (u & 0x80000000u) ? ~u : (u | 0x80000000u);
                            ldg[slot] = ((unsigned long long)u << 28) | (unsigned long long)jc2;
                        }
                    }
                    cnt += __popc(sub2);
                }
            }
        }
        bool bad = active && (cnt < KNN || cnt > CAPG);
        if (__ballot(bad) == 0ULL) break;         // wave-uniform exit
        active = bad;
        if (active) r2 = (cnt < KNN) ? r2 * 1.6f : r2 * 0.82f;
    }

    // fill orig-idx field (bits 14..27) so u64 order == lex (d, orig idx)
    for (int k = l16; k < cnt; k += 16) {
        unsigned long long key = ldg[k];
        int jc = (int)(key & 0x3FFFull);
        ldg[k] = (key & ~0x0FFFFFFFull) | ((unsigned long long)Ob[jc] << 14) | (unsigned long long)jc;
    }
    __syncthreads();

    // ---- stable top-30: rank by u64 key (keys unique) ----
    const double qx = (double)qp.x, qy = (double)qp.y, qz = (double)qp.z;
    double sx = 0.0, sy = 0.0, sz = 0.0;
    double sxx = 0.0, sxy = 0.0, sxz = 0.0, syy = 0.0, syz = 0.0, szz = 0.0;

    for (int k = l16; k < cnt; k += 16) {
        unsigned long long key = ldg[k];
        int rank = 0;
        for (int u = 0; u < cnt; ++u) rank += (ldg[u] < key) ? 1 : 0;
        if (rank < KNN) {                         // exactly 30 survivors
            float4 p = P[(int)(key & 0x3FFFull)];
            double ax = (double)p.x - qx, ay = (double)p.y - qy, az = (double)p.z - qz;
            sx += ax; sy += ay; sz += az;
            sxx = fma(ax, ax, sxx); sxy = fma(ax, ay, sxy); sxz = fma(ax, az, sxz);
            syy = fma(ay, ay, syy); syz = fma(ay, az, syz); szz = fma(az, az, szz);
        }
    }

    #pragma unroll
    for (int off = 1; off < 16; off <<= 1) {
        sx  += __shfl_xor(sx,  off, 16); sy  += __shfl_xor(sy,  off, 16); sz  += __shfl_xor(sz,  off, 16);
        sxx += __shfl_xor(sxx, off, 16); sxy += __shfl_xor(sxy, off, 16); sxz += __shfl_xor(sxz, off, 16);
        syy += __shfl_xor(syy, off, 16); syz += __shfl_xor(syz, off, 16); szz += __shfl_xor(szz, off, 16);
    }

    if (l16 == 0) {
        const double kinv = 1.0 / (double)KNN;
        double m00 = sxx - sx * sx * kinv;
        double m11 = syy - sy * sy * kinv;
        double m22 = szz - sz * sz * kinv;
        double m01 = sxy - sx * sy * kinv;
        double m02 = sxz - sx * sz * kinv;
        double m12 = syz - sy * sz * kinv;

        double nx = 1.0, ny = 0.0, nz = 0.0;
        double q3 = (m00 + m11 + m22) / 3.0;
        double p1 = m01 * m01 + m02 * m02 + m12 * m12;
        double d00 = m00 - q3, d11 = m11 - q3, d22 = m22 - q3;
        double p2 = d00 * d00 + d11 * d11 + d22 * d22 + 2.0 * p1;
        if (p2 > 1e-280) {
            double pp = sqrt(p2 / 6.0);
            double ip = 1.0 / pp;
            double b00 = d00 * ip, b11 = d11 * ip, b22 = d22 * ip;
            double b01 = m01 * ip, b02 = m02 * ip, b12 = m12 * ip;
            double detB = b00 * (b11 * b22 - b12 * b12)
                        - b01 * (b01 * b22 - b12 * b02)
                        + b02 * (b01 * b12 - b11 * b02);
            double rr = 0.5 * detB;
            rr = rr < -1.0 ? -1.0 : (rr > 1.0 ? 1.0 : rr);
            double phi = acos(rr) / 3.0;
            double lam = q3 + 2.0 * pp * cos(phi + 2.0943951023931953); // smallest eig
            double a00 = m00 - lam, a11 = m11 - lam, a22 = m22 - lam;
            double v0x = m01 * m12 - m02 * a11, v0y = m02 * m01 - a00 * m12, v0z = a00 * a11 - m01 * m01;
            double v1x = m01 * a22 - m02 * m12, v1y = m02 * m02 - a00 * a22, v1z = a00 * m12 - m01 * m02;
            double v2x = a11 * a22 - m12 * m12, v2y = m12 * m02 - m01 * a22, v2z = m01 * m12 - a11 * m02;
            double n0 = v0x * v0x + v0y * v0y + v0z * v0z;
            double n1 = v1x * v1x + v1y * v1y + v1z * v1z;
            double n2 = v2x * v2x + v2y * v2y + v2z * v2z;
            double bx = v0x, by = v0y, bz = v0z, bn = n0;
            if (n1 > bn) { bx = v1x; by = v1y; bz = v1z; bn = n1; }
            if (n2 > bn) { bx = v2x; by = v2y; bz = v2z; bn = n2; }
            if (bn > 1e-280) {
                double inv = 1.0 / sqrt(bn);
                nx = bx * inv; ny = by * inv; nz = bz * inv;
            }
        }
        double dq = -(qx * nx + qy * ny + qz * nz);
        if (dq < 0.0) { nx = -nx; ny = -ny; nz = -nz; }

        float* ob = out + (size_t)b * 6 * N_PTS;
        ob[3 * N_PTS + oi] = (float)nx;
        ob[4 * N_PTS + oi] = (float)ny;
        ob[5 * N_PTS + oi] = (float)nz;
    }
}

// ---------------------------------------------------------------------------
extern "C" void kernel_launch(void* const* d_in, const int* in_sizes, int n_in,
                              void* d_out, int out_size, void* d_ws, size_t ws_size,
                              hipStream_t stream) {
    const float* x = (const float*)d_in[0];
    float* out = (float*)d_out;
    char* ws = (char*)d_ws;
    float4* S    = (float4*)(ws);                 // 512 KB
    int*    O    = (int*)(ws + 524288);           // 128 KB
    int*    bsta = (int*)(ws + 655360);           // 4*4097*4 = 65552 B

    prep_kernel<<<dim3(4), dim3(1024), 0, stream>>>(x, S, O, bsta, out);
    knn_normal_kernel<<<dim3(32768 / GROUPS), dim3(BLOCK), 0, stream>>>(S, O, bsta, out);
}